// Round 24
// baseline (220.537 us; speedup 1.0000x reference)
//
#include <hip/hip_runtime.h>
#include <cmath>

#define BATCH 64
#define SEQL  32
#define EMBD  300
#define HIDD  500
#define NOBJ  64
#define GHID  100
#define ANSN  1000
#define MCOL  2048   // t*64+b column dimension

// partition: 4 batch-groups x 25 unit-blocks
#define GRP    4
#define GBATCH 16
#define BPG    25
#define UPB8   20
#define NBLK   (GRP*BPG)   // 100 lstm blocks
#define NXG    256         // xg worker blocks (8 tc x 32 n-tiles)
#define SLOTP  32          // slot padding in ints (128 B)

#define KPADX  328         // xg LDS row stride in f16 (656 B)
#define TCH    4           // timesteps per xg block

// k_pair5 LDS layout (pre-MFMA staging region aliased by epilogue arrays)
#define SM_CONV   0        // float [24][64]   = 6144
#define SM_G1IJ   6144     // float [100][48]  = 19200
#define SM_HB     25344    // float [512]      = 2048
#define SM_QPL    27392    // float [112]      = 448   (pre total 27840)
#define SM_REDX   0        // float [4][112]   = 1792  (post, aliases conv)
#define SM_GS     1792     // float [112]
#define SM_FH     2240     // float [112]
#define SM_LG     2688     // float [1000]
#define SM_RED    6688     // float [4]
#define SM_RED2   6704     // float [4]
#define SM_LASTF  6720     // int
#define SM_JPL    27840    // f16 [64][136]    = 17408
#define SM_BASEL  45248    // f16 [16][136]    = 4352
#define SM_G2H    49600    // f16 [112][136]   = 30464
#define SM_TOTAL  80064

typedef _Float16 half8 __attribute__((ext_vector_type(8)));
typedef float    f32x4 __attribute__((ext_vector_type(4)));

__device__ __forceinline__ float sigmf(float x){ return 1.f/(1.f+expf(-x)); }

// sc1 (coherence-point) primitives: RELAXED agent-scope atomics, no cache-wide fences
__device__ __forceinline__ unsigned long long ld_cc8(const unsigned long long* p){
    return __hip_atomic_load(p, __ATOMIC_RELAXED, __HIP_MEMORY_SCOPE_AGENT);
}
__device__ __forceinline__ void st_cc8(_Float16* p, unsigned long long v){
    __hip_atomic_store((unsigned long long*)p, v, __ATOMIC_RELAXED, __HIP_MEMORY_SCOPE_AGENT);
}
__device__ __forceinline__ float ld_cc4(const float* p){
    return __hip_atomic_load(p, __ATOMIC_RELAXED, __HIP_MEMORY_SCOPE_AGENT);
}
__device__ __forceinline__ void st_cc4(float* p, float v){
    __hip_atomic_store(p, v, __ATOMIC_RELAXED, __HIP_MEMORY_SCOPE_AGENT);
}

// group-local all-to-all barrier (one hop, fence-free; proven r8-r23)
__device__ __forceinline__ void gbarA(int* slots, int grp, int ub, int seq)
{
    __syncthreads();
    if (threadIdx.x == 0)
        __hip_atomic_store(slots + (grp*BPG + ub)*SLOTP, seq,
                           __ATOMIC_RELAXED, __HIP_MEMORY_SCOPE_AGENT);
    if (threadIdx.x < BPG){
        int* s = slots + (grp*BPG + threadIdx.x)*SLOTP;
        while (__hip_atomic_load(s, __ATOMIC_RELAXED, __HIP_MEMORY_SCOPE_AGENT) < seq)
            __builtin_amdgcn_s_sleep(1);
    }
    asm volatile("" ::: "memory");
    __syncthreads();
}

// wave-local h pack (r20-proven)
__device__ __forceinline__ void pack_store_h(
    _Float16* hF, int buf, int grp, int u0, int w, int lane, float hval)
{
    union { _Float16 f; unsigned short s; } cv;
    cv.f = (_Float16)hval;
    unsigned int h2 = cv.s;
    int base = lane & 15;
    unsigned int x0 = (unsigned int)__shfl((int)h2, base +  0, 64);
    unsigned int x1 = (unsigned int)__shfl((int)h2, base + 16, 64);
    unsigned int x2 = (unsigned int)__shfl((int)h2, base + 32, 64);
    unsigned int x3 = (unsigned int)__shfl((int)h2, base + 48, 64);
    if (lane < 16){
        unsigned long long v = (unsigned long long)(x0 & 0xFFFFu)
                             | ((unsigned long long)(x1 & 0xFFFFu) << 16)
                             | ((unsigned long long)(x2 & 0xFFFFu) << 32)
                             | ((unsigned long long)(x3 & 0xFFFFu) << 48);
        st_cc8(hF + ((size_t)(buf*GRP + grp)*GBATCH + lane)*512 + u0 + w*4, v);
    }
}

// ---------------- k_mega: blocks 0..99 = LSTM (XCD-affine groups), 100..355 = xg workers ----------------
__global__ __launch_bounds__(320, 1) void k_mega(
    const int* __restrict__ sent, const float* __restrict__ table,
    const float* __restrict__ Wih, const float* __restrict__ b_ih, const float* __restrict__ b_hh,
    _Float16* __restrict__ hF, float* __restrict__ hqB, float* __restrict__ xgT,
    const float* __restrict__ Whh, const float* __restrict__ h0, const float* __restrict__ c0,
    const int* __restrict__ lens, int* __restrict__ slots, int* __restrict__ xgdone)
{
    __shared__ __align__(16) char smem[102400];

    int tid = threadIdx.x, bid = blockIdx.x;
    int w = tid >> 6, lane = tid & 63;

    if (bid >= NBLK){
        _Float16* Sh  = (_Float16*)smem;                 // [64*KPADX] = 41984 B
        int*      sidx= (int*)(smem + 41984);            // [TCH][64]
        int xb = bid - NBLK;
        int tc = xb >> 5;                 // 0..7
        int n0 = (xb & 31) * 64;
        int rA = lane & 15, kb = lane >> 4;

        for (int i = tid; i < TCH*64; i += 320){
            int tt = i >> 6, b = i & 63;
            sidx[tt*64 + b] = sent[b*SEQL + tc*TCH + tt];
        }
        for (int i = tid; i < 64*75; i += 320){
            int n = i / 75, c4 = i - (i/75)*75;
            float4 v = {0.f,0.f,0.f,0.f};
            if (n0 + n < 2000)
                v = *(const float4*)(Wih + (size_t)(n0+n)*300 + c4*4);
            _Float16* dst = &Sh[n*KPADX + c4*4];
            dst[0]=(_Float16)v.x; dst[1]=(_Float16)v.y; dst[2]=(_Float16)v.z; dst[3]=(_Float16)v.w;
        }
        for (int i = tid; i < 64*20; i += 320){   // zero pad k 300..319
            int n = i / 20, k = 300 + (i - (i/20)*20);
            Sh[n*KPADX + k] = (_Float16)0.f;
        }
        __syncthreads();
        half8 areg[10];
        float biasr[4];
        if (w < 4){
            #pragma unroll
            for (int ks = 0; ks < 10; ++ks)
                areg[ks] = *(const half8*)&Sh[(w*16 + rA)*KPADX + ks*32 + kb*8];
            #pragma unroll
            for (int r = 0; r < 4; ++r){
                int n = n0 + w*16 + kb*4 + r;
                biasr[r] = (n < 2000) ? b_ih[n] + b_hh[n] : 0.f;
            }
        }
        __syncthreads();   // all A reads done before B overwrites Sh

        for (int tt = 0; tt < TCH; ++tt){
            for (int i = tid; i < 64*75; i += 320){
                int m = i / 75, c4 = i - (i/75)*75;
                float4 v = *(const float4*)(table + (size_t)sidx[tt*64 + m]*300 + c4*4);
                _Float16* dst = &Sh[m*KPADX + c4*4];
                dst[0]=(_Float16)v.x; dst[1]=(_Float16)v.y; dst[2]=(_Float16)v.z; dst[3]=(_Float16)v.w;
            }
            for (int i = tid; i < 64*20; i += 320){
                int m = i / 20, k = 300 + (i - (i/20)*20);
                Sh[m*KPADX + k] = (_Float16)0.f;
            }
            __syncthreads();

            if (w < 4){
                f32x4 acc[4] = {};
                #pragma unroll
                for (int ks = 0; ks < 10; ++ks){
                    #pragma unroll
                    for (int mc = 0; mc < 4; ++mc){
                        half8 bf = *(const half8*)&Sh[(mc*16 + rA)*KPADX + ks*32 + kb*8];
                        acc[mc] = __builtin_amdgcn_mfma_f32_16x16x32_f16(areg[ks], bf, acc[mc], 0, 0, 0);
                    }
                }
                #pragma unroll
                for (int r = 0; r < 4; ++r){
                    int n = n0 + w*16 + kb*4 + r;
                    if (n < 2000){
                        #pragma unroll
                        for (int mc = 0; mc < 4; ++mc)
                            st_cc4(xgT + (size_t)n*MCOL + (tc*TCH+tt)*64 + mc*16 + rA,
                                   acc[mc][r] + biasr[r]);
                    }
                }
            }
            __syncthreads();
        }
        if (tid == 0)
            __hip_atomic_fetch_add(xgdone + tc*SLOTP, 1,
                                   __ATOMIC_RELAXED, __HIP_MEMORY_SCOPE_AGENT);
        return;
    }

    // ======== LSTM (r22 path; XCD-affine grouping: group g on XCDs {g, g+4}) ========
    _Float16* Wl  = (_Float16*)smem;                 // [80*512] swizzled, 81920 B
    float*    gl  = (float*)(smem + 81920);          // [4*80*16], 20480 B

    int grp = bid & 3, ub = bid >> 2;          // XCD-affine relabel (was bid/BPG, bid%BPG)
    int u0  = ub * UPB8;

    int pb  = tid & 15, puu = tid >> 4;        // puu 0..19
    int pu  = u0 + puu;
    int gb  = grp*GBATCH + pb;                 // global batch row
    float cprev = c0[gb*HIDD + pu];
    float hprev = h0[gb*HIDD + pu];
    int   mylen = lens[gb];

    for (int i = tid; i < 80*512; i += 320){
        int m = i >> 9, k = i & 511;
        int g = m / UPB8, uu = m - g*UPB8;
        float v = (k < HIDD) ? Whh[(size_t)(g*HIDD + u0 + uu)*HIDD + k] : 0.f;
        int off = (i*2) ^ ((m & 7) << 4);
        *(_Float16*)((char*)Wl + off) = (_Float16)v;
    }
    pack_store_h(hF, 1, grp, u0, w, lane, hprev);
    if (ub == 0 && tid >= 128 && tid < 224){   // zero k-pad 500..511, both buffers
        int j = tid - 128;
        int buf = j / 48, r = j - buf*48;
        int b = r / 3, q = r - (r/3)*3;
        st_cc8(hF + ((size_t)(buf*GRP + grp)*GBATCH + b)*512 + 500 + q*4, 0ULL);
    }
    gbarA(slots, grp, ub, 1);

    const int mA = lane & 15, kb = lane >> 4;

    for (int t = 0; t < SEQL; ++t){
        if ((t & 3) == 0){
            if (tid == 0){
                const int* f = xgdone + (t >> 2)*SLOTP;
                while (__hip_atomic_load(f, __ATOMIC_RELAXED, __HIP_MEMORY_SCOPE_AGENT) < 32)
                    __builtin_amdgcn_s_sleep(1);
            }
            asm volatile("" ::: "memory");
            __syncthreads();
        }

        const _Float16* hsrc = hF + (size_t)(((t&1)^1)*GRP + grp)*GBATCH*512;

        float xgv[4];
        #pragma unroll
        for (int g = 0; g < 4; ++g)
            xgv[g] = ld_cc4(xgT + (size_t)(g*HIDD + pu)*MCOL + t*64 + gb);

        if (w < 4){
            half8 bf[4];
            #pragma unroll
            for (int ks4 = 0; ks4 < 4; ++ks4){
                int ke = (w*4 + ks4)*32 + kb*8;            // f16 element offset in row
                const unsigned long long* p =
                    (const unsigned long long*)(hsrc + mA*512 + ke);
                union { unsigned long long q[2]; half8 h; } u;
                u.q[0] = ld_cc8(p);
                u.q[1] = ld_cc8(p + 1);
                bf[ks4] = u.h;
            }
            f32x4 acc[5] = {};
            #pragma unroll
            for (int rt = 0; rt < 5; ++rt){
                #pragma unroll
                for (int ks4 = 0; ks4 < 4; ++ks4){
                    int kByte = (w*4 + ks4)*64 + kb*16;
                    int m = rt*16 + mA;
                    int aOff = (m*1024 + kByte) ^ ((m & 7) << 4);
                    half8 af = *(const half8*)((const char*)Wl + aOff);
                    acc[rt] = __builtin_amdgcn_mfma_f32_16x16x32_f16(af, bf[ks4], acc[rt], 0, 0, 0);
                }
            }
            #pragma unroll
            for (int rt = 0; rt < 5; ++rt)
                #pragma unroll
                for (int r = 0; r < 4; ++r)
                    gl[(w*80 + rt*16 + kb*4 + r)*16 + mA] = acc[rt][r];
        }
        __syncthreads();

        {
            float g4[4];
            #pragma unroll
            for (int g = 0; g < 4; ++g){
                int row = g*UPB8 + puu;
                float s = gl[(0*80 + row)*16 + pb] + gl[(1*80 + row)*16 + pb]
                        + gl[(2*80 + row)*16 + pb] + gl[(3*80 + row)*16 + pb];
                s += xgv[g];
                g4[g] = s;
            }
            float si = sigmf(g4[0]), sf = sigmf(g4[1]);
            float tg = tanhf(g4[2]), so = sigmf(g4[3]);
            float cn = sf*cprev + si*tg;
            float hn = so*tanhf(cn);
            if (t < mylen){ cprev = cn; hprev = hn; }
        }
        if (t == SEQL-1){
            hqB[(size_t)gb*512 + pu] = hprev;   // final h, [b][512] f32
        } else {
            pack_store_h(hF, t & 1, grp, u0, w, lane, hprev);
            gbarA(slots, grp, ub, t + 2);
        }
    }
}

// ---------------- k_pair5: qp (2-way split) + ip/jp + pair MFMA + epilogue ----------------
__global__ __launch_bounds__(256, 1) void k_pair5(
    const float* __restrict__ hqB, const float* __restrict__ conv,
    const float* __restrict__ g1w, const float* __restrict__ g1b,
    const float* __restrict__ g2w, const float* __restrict__ g2b,
    const float* __restrict__ f1w, const float* __restrict__ f1b,
    const float* __restrict__ f2w, const float* __restrict__ f2b,
    float* __restrict__ part, int* __restrict__ pcnt, float* __restrict__ out)
{
    __shared__ __align__(16) char smem[SM_TOTAL];
    float*    convl = (float*)(smem + SM_CONV);
    float*    g1ij  = (float*)(smem + SM_G1IJ);
    float*    hb    = (float*)(smem + SM_HB);
    float*    qpl   = (float*)(smem + SM_QPL);
    _Float16* jpl   = (_Float16*)(smem + SM_JPL);
    _Float16* basel = (_Float16*)(smem + SM_BASEL);
    _Float16* g2h   = (_Float16*)(smem + SM_G2H);

    int b  = blockIdx.x >> 2;
    int ic = blockIdx.x & 3;
    int tid = threadIdx.x;
    int w = tid >> 6, lane = tid & 63;
    int ncol = lane & 15, kb = lane >> 4;

    // phase 1: stage shared inputs
    for (int i = tid; i < 24*64; i += 256)
        convl[i] = conv[(size_t)b*24*64 + i];
    for (int i = tid; i < 100*48; i += 256){
        int n = i/48, c = i - n*48;
        g1ij[n*48 + c] = g1w[(size_t)n*548 + 500 + c];
    }
    for (int i = tid; i < 512; i += 256) hb[i] = hqB[(size_t)b*512 + i];
    for (int i = tid; i < 112*136; i += 256){
        int n = i/136, k = i - n*136;
        g2h[n*136 + k] = (n < 100 && k < 100) ? (_Float16)g2w[n*GHID + k] : (_Float16)0.f;
    }
    __syncthreads();

    // phase 2: qpl split 2-way (n = tid>>1, k-half = tid&1) + jpl (f16)
    if (tid < 200){
        int n = tid >> 1, h = tid & 1;
        const float4* wr = (const float4*)(g1w + (size_t)n*548) + h*63;
        const float*  hv = hb + h*252;
        int cnt = h ? 62 : 63;          // halves: k4 0..62 / 63..124
        float s = 0.f;
        #pragma unroll 5
        for (int k4 = 0; k4 < 63; ++k4){
            if (k4 < cnt){
                float4 v = wr[k4];
                s += v.x*hv[k4*4] + v.y*hv[k4*4+1] + v.z*hv[k4*4+2] + v.w*hv[k4*4+3];
            }
        }
        s += __shfl_xor(s, 1);
        if (h == 0) qpl[n] = s + g1b[n];
    }
    for (int i = tid; i < NOBJ*100; i += 256){
        int o = i / 100, n = i - (i/100)*100;
        float sj = 0.f;
        #pragma unroll
        for (int c = 0; c < 24; ++c) sj += convl[c*64 + o] * g1ij[n*48 + c];
        jpl[o*136 + n] = (_Float16)sj;
    }
    for (int i = tid; i < NOBJ*36; i += 256)
        jpl[(i/36)*136 + 100 + (i - (i/36)*36)] = (_Float16)0.f;
    __syncthreads();   // qpl ready

    // phase 3: basel = f16(qpl + ip) for own 16 i-rows
    for (int i = tid; i < 16*136; i += 256){
        int il = i / 136, k = i - il*136;
        float v = 0.f;
        if (k < 100){
            float si = 0.f;
            int o = ic*16 + il;
            #pragma unroll
            for (int c = 0; c < 24; ++c) si += convl[c*64 + o] * g1ij[k*48 + 24 + c];
            v = qpl[k] + si;
        }
        basel[il*136 + k] = (_Float16)v;
    }
    float gb7[7];
    #pragma unroll
    for (int nt = 0; nt < 7; ++nt){
        int n = nt*16 + ncol;
        gb7[nt] = (n < 100) ? g2b[n] : 0.f;
    }
    __syncthreads();

    // phase 4: hoist g2h B-fragments into registers (r23-proven)
    half8 bfh[28];
    #pragma unroll
    for (int nt = 0; nt < 7; ++nt)
        #pragma unroll
        for (int ks = 0; ks < 4; ++ks)
            bfh[nt*4 + ks] = *(const half8*)&g2h[(nt*16 + ncol)*136 + ks*32 + kb*8];

    f32x4 sacc[7] = {};
    #pragma unroll 1
    for (int jc = 0; jc < 4; ++jc){
        int jrow = jc*16 + ncol;
        half8 jvh[4];
        #pragma unroll
        for (int ks = 0; ks < 4; ++ks)
            jvh[ks] = *(const half8*)&jpl[jrow*136 + ks*32 + kb*8];
        #pragma unroll 1
        for (int it = 0; it < 4; ++it){
            int il = w*4 + it;
            f32x4 acc[7] = {};
            #pragma unroll
            for (int ks = 0; ks < 4; ++ks){
                half8 bv = *(const half8*)&basel[il*136 + ks*32 + kb*8];
                half8 af;
                #pragma unroll
                for (int e = 0; e < 8; ++e){
                    _Float16 s = jvh[ks][e] + bv[e];
                    af[e] = (s > (_Float16)0.f) ? s : (_Float16)0.f;
                }
                #pragma unroll
                for (int nt = 0; nt < 7; ++nt)
                    acc[nt] = __builtin_amdgcn_mfma_f32_16x16x32_f16(af, bfh[nt*4 + ks], acc[nt], 0, 0, 0);
            }
            #pragma unroll
            for (int nt = 0; nt < 7; ++nt)
                #pragma unroll
                for (int r = 0; r < 4; ++r)
                    sacc[nt][r] += fmaxf(acc[nt][r] + gb7[nt], 0.f);
        }
    }
    // staging region dead from here -> epilogue arrays alias it
    float* redx = (float*)(smem + SM_REDX);
    #pragma unroll
    for (int nt = 0; nt < 7; ++nt){
        float s = sacc[nt][0] + sacc[nt][1] + sacc[nt][2] + sacc[nt][3];
        s += __shfl_xor(s, 16);
        s += __shfl_xor(s, 32);
        if (lane < 16) redx[w*112 + nt*16 + lane] = s;
    }
    __syncthreads();
    if (tid < 100){
        float p = redx[0*112+tid] + redx[1*112+tid] + redx[2*112+tid] + redx[3*112+tid];
        st_cc4(part + (size_t)(b*4 + ic)*GHID + tid, p);
    }
    __syncthreads();   // drain part stores before counter RMW

    int* lastf = (int*)(smem + SM_LASTF);
    if (tid == 0){
        int old = __hip_atomic_fetch_add(pcnt + b*SLOTP, 1,
                                         __ATOMIC_RELAXED, __HIP_MEMORY_SCOPE_AGENT);
        *lastf = (old == 3);
    }
    __syncthreads();
    if (!*lastf) return;

    // ---- epilogue (last block for this b) ----
    float* gs  = (float*)(smem + SM_GS);
    float* fh  = (float*)(smem + SM_FH);
    float* lg  = (float*)(smem + SM_LG);
    float* red = (float*)(smem + SM_RED);
    float* red2= (float*)(smem + SM_RED2);

    if (tid < 100){
        float s = 0.f;
        #pragma unroll
        for (int ic2 = 0; ic2 < 4; ++ic2)
            s += ld_cc4(part + (size_t)(b*4 + ic2)*GHID + tid);
        gs[tid] = s;
    }
    __syncthreads();
    if (tid < 100){
        const float4* wr = (const float4*)(f1w + (size_t)tid*GHID);
        float s = f1b[tid];
        #pragma unroll 5
        for (int k4 = 0; k4 < 25; ++k4){
            float4 v = wr[k4];
            s += v.x*gs[k4*4] + v.y*gs[k4*4+1] + v.z*gs[k4*4+2] + v.w*gs[k4*4+3];
        }
        fh[tid] = fmaxf(s, 0.f);
    }
    __syncthreads();
    for (int n = tid; n < ANSN; n += 256){
        const float4* wr = (const float4*)(f2w + (size_t)n*GHID);
        float s = f2b[n];
        #pragma unroll 5
        for (int k4 = 0; k4 < 25; ++k4){
            float4 v = wr[k4];
            s += v.x*fh[k4*4] + v.y*fh[k4*4+1] + v.z*fh[k4*4+2] + v.w*fh[k4*4+3];
        }
        lg[n] = fmaxf(s, 0.f);
    }
    __syncthreads();
    float mx = -1e30f;
    for (int n = tid; n < ANSN; n += 256) mx = fmaxf(mx, lg[n]);
    #pragma unroll
    for (int off = 32; off > 0; off >>= 1) mx = fmaxf(mx, __shfl_xor(mx, off));
    if ((tid & 63) == 0) red[tid >> 6] = mx;
    __syncthreads();
    mx = fmaxf(fmaxf(red[0], red[1]), fmaxf(red[2], red[3]));
    float se = 0.f;
    for (int n = tid; n < ANSN; n += 256) se += expf(lg[n]-mx);
    #pragma unroll
    for (int off = 32; off > 0; off >>= 1) se += __shfl_xor(se, off);
    if ((tid & 63) == 0) red2[tid >> 6] = se;
    __syncthreads();
    se = red2[0]+red2[1]+red2[2]+red2[3];
    float lse = logf(se);
    for (int n = tid; n < ANSN; n += 256) out[(size_t)b*ANSN + n] = lg[n] - mx - lse;
}

extern "C" void kernel_launch(void* const* d_in, const int* in_sizes, int n_in,
                              void* d_out, int out_size, void* d_ws, size_t ws_size,
                              hipStream_t stream)
{
    const int*   sent  = (const int*)  d_in[0];
    const float* conv  = (const float*)d_in[1];
    const int*   lens  = (const int*)  d_in[2];
    const float* table = (const float*)d_in[3];
    const float* W_ih  = (const float*)d_in[4];
    const float* W_hh  = (const float*)d_in[5];
    const float* b_ih  = (const float*)d_in[6];
    const float* b_hh  = (const float*)d_in[7];
    const float* h0    = (const float*)d_in[8];
    const float* c0    = (const float*)d_in[9];
    const float* g1_w  = (const float*)d_in[10];
    const float* g1_b  = (const float*)d_in[11];
    const float* g2_w  = (const float*)d_in[12];
    const float* g2_b  = (const float*)d_in[13];
    const float* f1_w  = (const float*)d_in[14];
    const float* f1_b  = (const float*)d_in[15];
    const float* f2_w  = (const float*)d_in[16];
    const float* f2_b  = (const float*)d_in[17];
    float* out = (float*)d_out;

    float* ws    = (float*)d_ws;
    int*   slots = (int*)d_ws;                          // [0, 3200) ints
    int*   xgdone= (int*)d_ws + NBLK*SLOTP;             // [3200, 3456) ints
    int*   pcnt  = (int*)d_ws + NBLK*SLOTP + 8*SLOTP;   // [3456, 5504) ints
    _Float16* hF = (_Float16*)(ws + 16384);             // 2*4*16*512 f16 = 128 KB
    float* hqB  = ws + 16384 + 32768;                   // 64*512 f32
    float* xgT  = hqB + 64*512;                         // 2000*2048 f32
    float* part = xgT + (size_t)4*HIDD*MCOL;            // 256*100

    // 0. zero barrier slots + xg flags + pair counters (deterministic across replays)
    hipMemsetAsync(slots, 0, (NBLK + 8 + BATCH)*SLOTP*sizeof(int), stream);

    // 1. fused xg + LSTM: 356 blocks (100 lstm + 256 xg workers)
    k_mega<<<NBLK + NXG, 320, 0, stream>>>(sent, table, W_ih, b_ih, b_hh,
                                           hF, hqB, xgT, W_hh, h0, c0, lens,
                                           slots, xgdone);

    // 2. fused qp/ipjp + pair MFMA + final epilogue (256 blocks)
    k_pair5<<<BATCH*4, 256, 0, stream>>>(hqB, conv, g1_w, g1_b, g2_w, g2_b,
                                         f1_w, f1_b, f2_w, f2_b, part, pcnt, out);
}

// Round 25
// 212.825 us; speedup vs baseline: 1.0362x; 1.0362x over previous
//
#include <hip/hip_runtime.h>
#include <cmath>

#define BATCH 64
#define SEQL  32
#define EMBD  300
#define HIDD  500
#define NOBJ  64
#define GHID  100
#define ANSN  1000
#define MCOL  2048   // t*64+b column dimension

// partition: 4 batch-groups x 25 unit-blocks
#define GRP    4
#define GBATCH 16
#define BPG    25
#define UPB8   20
#define NBLK   (GRP*BPG)   // 100 lstm blocks
#define NXG    256         // xg worker blocks (8 tc x 32 n-tiles)
#define SLOTP  32          // slot padding in ints (128 B)

#define KPADX  328         // xg LDS row stride in f16 (656 B)
#define TCH    4           // timesteps per xg block

// k_pair5 LDS layout (pre-MFMA staging region aliased by epilogue arrays)
#define SM_CONV   0        // float [24][64]   = 6144
#define SM_G1IJ   6144     // float [100][48]  = 19200
#define SM_HB     25344    // float [512]      = 2048
#define SM_QPL    27392    // float [112]      = 448   (pre total 27840)
#define SM_REDX   0        // float [4][112]   = 1792  (post, aliases conv)
#define SM_GS     1792     // float [112]
#define SM_FH     2240     // float [112]
#define SM_LG     2688     // float [1000]
#define SM_RED    6688     // float [4]
#define SM_RED2   6704     // float [4]
#define SM_LASTF  6720     // int
#define SM_JPL    27840    // f16 [64][136]    = 17408
#define SM_BASEL  45248    // f16 [16][136]    = 4352
#define SM_G2H    49600    // f16 [112][136]   = 30464
#define SM_TOTAL  80064

typedef _Float16 half8 __attribute__((ext_vector_type(8)));
typedef float    f32x4 __attribute__((ext_vector_type(4)));

__device__ __forceinline__ float sigmf(float x){ return 1.f/(1.f+expf(-x)); }

// sc1 (coherence-point) primitives: RELAXED agent-scope atomics, no cache-wide fences
__device__ __forceinline__ unsigned long long ld_cc8(const unsigned long long* p){
    return __hip_atomic_load(p, __ATOMIC_RELAXED, __HIP_MEMORY_SCOPE_AGENT);
}
__device__ __forceinline__ void st_cc8(_Float16* p, unsigned long long v){
    __hip_atomic_store((unsigned long long*)p, v, __ATOMIC_RELAXED, __HIP_MEMORY_SCOPE_AGENT);
}
__device__ __forceinline__ float ld_cc4(const float* p){
    return __hip_atomic_load(p, __ATOMIC_RELAXED, __HIP_MEMORY_SCOPE_AGENT);
}
__device__ __forceinline__ void st_cc4(float* p, float v){
    __hip_atomic_store(p, v, __ATOMIC_RELAXED, __HIP_MEMORY_SCOPE_AGENT);
}

// group-local all-to-all barrier (one hop, fence-free; proven r8-r23)
__device__ __forceinline__ void gbarA(int* slots, int grp, int ub, int seq)
{
    __syncthreads();
    if (threadIdx.x == 0)
        __hip_atomic_store(slots + (grp*BPG + ub)*SLOTP, seq,
                           __ATOMIC_RELAXED, __HIP_MEMORY_SCOPE_AGENT);
    if (threadIdx.x < BPG){
        int* s = slots + (grp*BPG + threadIdx.x)*SLOTP;
        while (__hip_atomic_load(s, __ATOMIC_RELAXED, __HIP_MEMORY_SCOPE_AGENT) < seq)
            __builtin_amdgcn_s_sleep(1);
    }
    asm volatile("" ::: "memory");
    __syncthreads();
}

// wave-local h pack (r20-proven)
__device__ __forceinline__ void pack_store_h(
    _Float16* hF, int buf, int grp, int u0, int w, int lane, float hval)
{
    union { _Float16 f; unsigned short s; } cv;
    cv.f = (_Float16)hval;
    unsigned int h2 = cv.s;
    int base = lane & 15;
    unsigned int x0 = (unsigned int)__shfl((int)h2, base +  0, 64);
    unsigned int x1 = (unsigned int)__shfl((int)h2, base + 16, 64);
    unsigned int x2 = (unsigned int)__shfl((int)h2, base + 32, 64);
    unsigned int x3 = (unsigned int)__shfl((int)h2, base + 48, 64);
    if (lane < 16){
        unsigned long long v = (unsigned long long)(x0 & 0xFFFFu)
                             | ((unsigned long long)(x1 & 0xFFFFu) << 16)
                             | ((unsigned long long)(x2 & 0xFFFFu) << 32)
                             | ((unsigned long long)(x3 & 0xFFFFu) << 48);
        st_cc8(hF + ((size_t)(buf*GRP + grp)*GBATCH + lane)*512 + u0 + w*4, v);
    }
}

// ---------------- k_mega: blocks 0..99 = LSTM, 100..355 = xg workers (r23 verbatim) ----------------
__global__ __launch_bounds__(320, 1) void k_mega(
    const int* __restrict__ sent, const float* __restrict__ table,
    const float* __restrict__ Wih, const float* __restrict__ b_ih, const float* __restrict__ b_hh,
    _Float16* __restrict__ hF, float* __restrict__ hqB, float* __restrict__ xgT,
    const float* __restrict__ Whh, const float* __restrict__ h0, const float* __restrict__ c0,
    const int* __restrict__ lens, int* __restrict__ slots, int* __restrict__ xgdone)
{
    __shared__ __align__(16) char smem[102400];

    int tid = threadIdx.x, bid = blockIdx.x;
    int w = tid >> 6, lane = tid & 63;

    if (bid >= NBLK){
        _Float16* Sh  = (_Float16*)smem;                 // [64*KPADX] = 41984 B
        int*      sidx= (int*)(smem + 41984);            // [TCH][64]
        int xb = bid - NBLK;
        int tc = xb >> 5;                 // 0..7
        int n0 = (xb & 31) * 64;
        int rA = lane & 15, kb = lane >> 4;

        for (int i = tid; i < TCH*64; i += 320){
            int tt = i >> 6, b = i & 63;
            sidx[tt*64 + b] = sent[b*SEQL + tc*TCH + tt];
        }
        for (int i = tid; i < 64*75; i += 320){
            int n = i / 75, c4 = i - (i/75)*75;
            float4 v = {0.f,0.f,0.f,0.f};
            if (n0 + n < 2000)
                v = *(const float4*)(Wih + (size_t)(n0+n)*300 + c4*4);
            _Float16* dst = &Sh[n*KPADX + c4*4];
            dst[0]=(_Float16)v.x; dst[1]=(_Float16)v.y; dst[2]=(_Float16)v.z; dst[3]=(_Float16)v.w;
        }
        for (int i = tid; i < 64*20; i += 320){   // zero pad k 300..319
            int n = i / 20, k = 300 + (i - (i/20)*20);
            Sh[n*KPADX + k] = (_Float16)0.f;
        }
        __syncthreads();
        half8 areg[10];
        float biasr[4];
        if (w < 4){
            #pragma unroll
            for (int ks = 0; ks < 10; ++ks)
                areg[ks] = *(const half8*)&Sh[(w*16 + rA)*KPADX + ks*32 + kb*8];
            #pragma unroll
            for (int r = 0; r < 4; ++r){
                int n = n0 + w*16 + kb*4 + r;
                biasr[r] = (n < 2000) ? b_ih[n] + b_hh[n] : 0.f;
            }
        }
        __syncthreads();   // all A reads done before B overwrites Sh

        for (int tt = 0; tt < TCH; ++tt){
            for (int i = tid; i < 64*75; i += 320){
                int m = i / 75, c4 = i - (i/75)*75;
                float4 v = *(const float4*)(table + (size_t)sidx[tt*64 + m]*300 + c4*4);
                _Float16* dst = &Sh[m*KPADX + c4*4];
                dst[0]=(_Float16)v.x; dst[1]=(_Float16)v.y; dst[2]=(_Float16)v.z; dst[3]=(_Float16)v.w;
            }
            for (int i = tid; i < 64*20; i += 320){
                int m = i / 20, k = 300 + (i - (i/20)*20);
                Sh[m*KPADX + k] = (_Float16)0.f;
            }
            __syncthreads();

            if (w < 4){
                f32x4 acc[4] = {};
                #pragma unroll
                for (int ks = 0; ks < 10; ++ks){
                    #pragma unroll
                    for (int mc = 0; mc < 4; ++mc){
                        half8 bf = *(const half8*)&Sh[(mc*16 + rA)*KPADX + ks*32 + kb*8];
                        acc[mc] = __builtin_amdgcn_mfma_f32_16x16x32_f16(areg[ks], bf, acc[mc], 0, 0, 0);
                    }
                }
                #pragma unroll
                for (int r = 0; r < 4; ++r){
                    int n = n0 + w*16 + kb*4 + r;
                    if (n < 2000){
                        #pragma unroll
                        for (int mc = 0; mc < 4; ++mc)
                            st_cc4(xgT + (size_t)n*MCOL + (tc*TCH+tt)*64 + mc*16 + rA,
                                   acc[mc][r] + biasr[r]);
                    }
                }
            }
            __syncthreads();
        }
        if (tid == 0)
            __hip_atomic_fetch_add(xgdone + tc*SLOTP, 1,
                                   __ATOMIC_RELAXED, __HIP_MEMORY_SCOPE_AGENT);
        return;
    }

    // ======== LSTM (r22/r23 path) ========
    _Float16* Wl  = (_Float16*)smem;                 // [80*512] swizzled, 81920 B
    float*    gl  = (float*)(smem + 81920);          // [4*80*16], 20480 B

    int grp = bid / BPG, ub = bid - grp*BPG;
    int u0  = ub * UPB8;

    int pb  = tid & 15, puu = tid >> 4;        // puu 0..19
    int pu  = u0 + puu;
    int gb  = grp*GBATCH + pb;                 // global batch row
    float cprev = c0[gb*HIDD + pu];
    float hprev = h0[gb*HIDD + pu];
    int   mylen = lens[gb];

    for (int i = tid; i < 80*512; i += 320){
        int m = i >> 9, k = i & 511;
        int g = m / UPB8, uu = m - g*UPB8;
        float v = (k < HIDD) ? Whh[(size_t)(g*HIDD + u0 + uu)*HIDD + k] : 0.f;
        int off = (i*2) ^ ((m & 7) << 4);
        *(_Float16*)((char*)Wl + off) = (_Float16)v;
    }
    pack_store_h(hF, 1, grp, u0, w, lane, hprev);
    if (ub == 0 && tid >= 128 && tid < 224){   // zero k-pad 500..511, both buffers
        int j = tid - 128;
        int buf = j / 48, r = j - buf*48;
        int b = r / 3, q = r - (r/3)*3;
        st_cc8(hF + ((size_t)(buf*GRP + grp)*GBATCH + b)*512 + 500 + q*4, 0ULL);
    }
    gbarA(slots, grp, ub, 1);

    const int mA = lane & 15, kb = lane >> 4;

    for (int t = 0; t < SEQL; ++t){
        if ((t & 3) == 0){
            if (tid == 0){
                const int* f = xgdone + (t >> 2)*SLOTP;
                while (__hip_atomic_load(f, __ATOMIC_RELAXED, __HIP_MEMORY_SCOPE_AGENT) < 32)
                    __builtin_amdgcn_s_sleep(1);
            }
            asm volatile("" ::: "memory");
            __syncthreads();
        }

        const _Float16* hsrc = hF + (size_t)(((t&1)^1)*GRP + grp)*GBATCH*512;

        float xgv[4];
        #pragma unroll
        for (int g = 0; g < 4; ++g)
            xgv[g] = ld_cc4(xgT + (size_t)(g*HIDD + pu)*MCOL + t*64 + gb);

        if (w < 4){
            half8 bf[4];
            #pragma unroll
            for (int ks4 = 0; ks4 < 4; ++ks4){
                int ke = (w*4 + ks4)*32 + kb*8;            // f16 element offset in row
                const unsigned long long* p =
                    (const unsigned long long*)(hsrc + mA*512 + ke);
                union { unsigned long long q[2]; half8 h; } u;
                u.q[0] = ld_cc8(p);
                u.q[1] = ld_cc8(p + 1);
                bf[ks4] = u.h;
            }
            f32x4 acc[5] = {};
            #pragma unroll
            for (int rt = 0; rt < 5; ++rt){
                #pragma unroll
                for (int ks4 = 0; ks4 < 4; ++ks4){
                    int kByte = (w*4 + ks4)*64 + kb*16;
                    int m = rt*16 + mA;
                    int aOff = (m*1024 + kByte) ^ ((m & 7) << 4);
                    half8 af = *(const half8*)((const char*)Wl + aOff);
                    acc[rt] = __builtin_amdgcn_mfma_f32_16x16x32_f16(af, bf[ks4], acc[rt], 0, 0, 0);
                }
            }
            #pragma unroll
            for (int rt = 0; rt < 5; ++rt)
                #pragma unroll
                for (int r = 0; r < 4; ++r)
                    gl[(w*80 + rt*16 + kb*4 + r)*16 + mA] = acc[rt][r];
        }
        __syncthreads();

        {
            float g4[4];
            #pragma unroll
            for (int g = 0; g < 4; ++g){
                int row = g*UPB8 + puu;
                float s = gl[(0*80 + row)*16 + pb] + gl[(1*80 + row)*16 + pb]
                        + gl[(2*80 + row)*16 + pb] + gl[(3*80 + row)*16 + pb];
                s += xgv[g];
                g4[g] = s;
            }
            float si = sigmf(g4[0]), sf = sigmf(g4[1]);
            float tg = tanhf(g4[2]), so = sigmf(g4[3]);
            float cn = sf*cprev + si*tg;
            float hn = so*tanhf(cn);
            if (t < mylen){ cprev = cn; hprev = hn; }
        }
        if (t == SEQL-1){
            hqB[(size_t)gb*512 + pu] = hprev;   // final h, [b][512] f32
        } else {
            pack_store_h(hF, t & 1, grp, u0, w, lane, hprev);
            gbarA(slots, grp, ub, t + 2);
        }
    }
}

// ---------------- k_pair5: qp + ip/jp + pair MFMA (B-operands register-hoisted) + epilogue ----------------
__global__ __launch_bounds__(256, 1) void k_pair5(
    const float* __restrict__ hqB, const float* __restrict__ conv,
    const float* __restrict__ g1w, const float* __restrict__ g1b,
    const float* __restrict__ g2w, const float* __restrict__ g2b,
    const float* __restrict__ f1w, const float* __restrict__ f1b,
    const float* __restrict__ f2w, const float* __restrict__ f2b,
    float* __restrict__ part, int* __restrict__ pcnt, float* __restrict__ out)
{
    __shared__ __align__(16) char smem[SM_TOTAL];
    float*    convl = (float*)(smem + SM_CONV);
    float*    g1ij  = (float*)(smem + SM_G1IJ);
    float*    hb    = (float*)(smem + SM_HB);
    float*    qpl   = (float*)(smem + SM_QPL);
    _Float16* jpl   = (_Float16*)(smem + SM_JPL);
    _Float16* basel = (_Float16*)(smem + SM_BASEL);
    _Float16* g2h   = (_Float16*)(smem + SM_G2H);

    int b  = blockIdx.x >> 2;
    int ic = blockIdx.x & 3;
    int tid = threadIdx.x;
    int w = tid >> 6, lane = tid & 63;
    int ncol = lane & 15, kb = lane >> 4;

    // phase 1: stage shared inputs
    for (int i = tid; i < 24*64; i += 256)
        convl[i] = conv[(size_t)b*24*64 + i];
    for (int i = tid; i < 100*48; i += 256){
        int n = i/48, c = i - n*48;
        g1ij[n*48 + c] = g1w[(size_t)n*548 + 500 + c];
    }
    for (int i = tid; i < 512; i += 256) hb[i] = hqB[(size_t)b*512 + i];
    for (int i = tid; i < 112*136; i += 256){
        int n = i/136, k = i - n*136;
        g2h[n*136 + k] = (n < 100 && k < 100) ? (_Float16)g2w[n*GHID + k] : (_Float16)0.f;
    }
    __syncthreads();

    // phase 2: qpl (f32) + jpl (f16) for all 64 j's
    if (tid < 100){
        const float4* wr = (const float4*)(g1w + (size_t)tid*548);
        float s = g1b[tid];
        #pragma unroll 5
        for (int k4 = 0; k4 < 125; ++k4){
            float4 v = wr[k4];
            s += v.x*hb[k4*4] + v.y*hb[k4*4+1] + v.z*hb[k4*4+2] + v.w*hb[k4*4+3];
        }
        qpl[tid] = s;
    }
    for (int i = tid; i < NOBJ*100; i += 256){
        int o = i / 100, n = i - (i/100)*100;
        float sj = 0.f;
        #pragma unroll
        for (int c = 0; c < 24; ++c) sj += convl[c*64 + o] * g1ij[n*48 + c];
        jpl[o*136 + n] = (_Float16)sj;
    }
    for (int i = tid; i < NOBJ*36; i += 256)
        jpl[(i/36)*136 + 100 + (i - (i/36)*36)] = (_Float16)0.f;
    __syncthreads();   // qpl ready

    // phase 3: basel = f16(qpl + ip) for own 16 i-rows
    for (int i = tid; i < 16*136; i += 256){
        int il = i / 136, k = i - il*136;
        float v = 0.f;
        if (k < 100){
            float si = 0.f;
            int o = ic*16 + il;
            #pragma unroll
            for (int c = 0; c < 24; ++c) si += convl[c*64 + o] * g1ij[k*48 + 24 + c];
            v = qpl[k] + si;
        }
        basel[il*136 + k] = (_Float16)v;
    }
    float gb7[7];
    #pragma unroll
    for (int nt = 0; nt < 7; ++nt){
        int n = nt*16 + ncol;
        gb7[nt] = (n < 100) ? g2b[n] : 0.f;
    }
    __syncthreads();

    // phase 4: hoist g2h B-fragments (28 half8, invariant over it/jc) into registers
    half8 bfh[28];
    #pragma unroll
    for (int nt = 0; nt < 7; ++nt)
        #pragma unroll
        for (int ks = 0; ks < 4; ++ks)
            bfh[nt*4 + ks] = *(const half8*)&g2h[(nt*16 + ncol)*136 + ks*32 + kb*8];

    f32x4 sacc[7] = {};
    #pragma unroll 1
    for (int jc = 0; jc < 4; ++jc){
        int jrow = jc*16 + ncol;
        half8 jvh[4];
        #pragma unroll
        for (int ks = 0; ks < 4; ++ks)
            jvh[ks] = *(const half8*)&jpl[jrow*136 + ks*32 + kb*8];
        #pragma unroll 1
        for (int it = 0; it < 4; ++it){
            int il = w*4 + it;
            f32x4 acc[7] = {};
            #pragma unroll
            for (int ks = 0; ks < 4; ++ks){
                half8 bv = *(const half8*)&basel[il*136 + ks*32 + kb*8];
                half8 af;
                #pragma unroll
                for (int e = 0; e < 8; ++e){
                    _Float16 s = jvh[ks][e] + bv[e];
                    af[e] = (s > (_Float16)0.f) ? s : (_Float16)0.f;
                }
                #pragma unroll
                for (int nt = 0; nt < 7; ++nt)
                    acc[nt] = __builtin_amdgcn_mfma_f32_16x16x32_f16(af, bfh[nt*4 + ks], acc[nt], 0, 0, 0);
            }
            #pragma unroll
            for (int nt = 0; nt < 7; ++nt)
                #pragma unroll
                for (int r = 0; r < 4; ++r)
                    sacc[nt][r] += fmaxf(acc[nt][r] + gb7[nt], 0.f);
        }
    }
    // staging region dead from here -> epilogue arrays alias it
    float* redx = (float*)(smem + SM_REDX);
    #pragma unroll
    for (int nt = 0; nt < 7; ++nt){
        float s = sacc[nt][0] + sacc[nt][1] + sacc[nt][2] + sacc[nt][3];
        s += __shfl_xor(s, 16);
        s += __shfl_xor(s, 32);
        if (lane < 16) redx[w*112 + nt*16 + lane] = s;
    }
    __syncthreads();
    if (tid < 100){
        float p = redx[0*112+tid] + redx[1*112+tid] + redx[2*112+tid] + redx[3*112+tid];
        st_cc4(part + (size_t)(b*4 + ic)*GHID + tid, p);
    }
    __syncthreads();   // drain part stores before counter RMW

    int* lastf = (int*)(smem + SM_LASTF);
    if (tid == 0){
        int old = __hip_atomic_fetch_add(pcnt + b*SLOTP, 1,
                                         __ATOMIC_RELAXED, __HIP_MEMORY_SCOPE_AGENT);
        *lastf = (old == 3);
    }
    __syncthreads();
    if (!*lastf) return;

    // ---- epilogue (last block for this b) ----
    float* gs  = (float*)(smem + SM_GS);
    float* fh  = (float*)(smem + SM_FH);
    float* lg  = (float*)(smem + SM_LG);
    float* red = (float*)(smem + SM_RED);
    float* red2= (float*)(smem + SM_RED2);

    if (tid < 100){
        float s = 0.f;
        #pragma unroll
        for (int ic2 = 0; ic2 < 4; ++ic2)
            s += ld_cc4(part + (size_t)(b*4 + ic2)*GHID + tid);
        gs[tid] = s;
    }
    __syncthreads();
    if (tid < 100){
        const float4* wr = (const float4*)(f1w + (size_t)tid*GHID);
        float s = f1b[tid];
        #pragma unroll 5
        for (int k4 = 0; k4 < 25; ++k4){
            float4 v = wr[k4];
            s += v.x*gs[k4*4] + v.y*gs[k4*4+1] + v.z*gs[k4*4+2] + v.w*gs[k4*4+3];
        }
        fh[tid] = fmaxf(s, 0.f);
    }
    __syncthreads();
    for (int n = tid; n < ANSN; n += 256){
        const float4* wr = (const float4*)(f2w + (size_t)n*GHID);
        float s = f2b[n];
        #pragma unroll 5
        for (int k4 = 0; k4 < 25; ++k4){
            float4 v = wr[k4];
            s += v.x*fh[k4*4] + v.y*fh[k4*4+1] + v.z*fh[k4*4+2] + v.w*fh[k4*4+3];
        }
        lg[n] = fmaxf(s, 0.f);
    }
    __syncthreads();
    float mx = -1e30f;
    for (int n = tid; n < ANSN; n += 256) mx = fmaxf(mx, lg[n]);
    #pragma unroll
    for (int off = 32; off > 0; off >>= 1) mx = fmaxf(mx, __shfl_xor(mx, off));
    if ((tid & 63) == 0) red[tid >> 6] = mx;
    __syncthreads();
    mx = fmaxf(fmaxf(red[0], red[1]), fmaxf(red[2], red[3]));
    float se = 0.f;
    for (int n = tid; n < ANSN; n += 256) se += expf(lg[n]-mx);
    #pragma unroll
    for (int off = 32; off > 0; off >>= 1) se += __shfl_xor(se, off);
    if ((tid & 63) == 0) red2[tid >> 6] = se;
    __syncthreads();
    se = red2[0]+red2[1]+red2[2]+red2[3];
    float lse = logf(se);
    for (int n = tid; n < ANSN; n += 256) out[(size_t)b*ANSN + n] = lg[n] - mx - lse;
}

extern "C" void kernel_launch(void* const* d_in, const int* in_sizes, int n_in,
                              void* d_out, int out_size, void* d_ws, size_t ws_size,
                              hipStream_t stream)
{
    const int*   sent  = (const int*)  d_in[0];
    const float* conv  = (const float*)d_in[1];
    const int*   lens  = (const int*)  d_in[2];
    const float* table = (const float*)d_in[3];
    const float* W_ih  = (const float*)d_in[4];
    const float* W_hh  = (const float*)d_in[5];
    const float* b_ih  = (const float*)d_in[6];
    const float* b_hh  = (const float*)d_in[7];
    const float* h0    = (const float*)d_in[8];
    const float* c0    = (const float*)d_in[9];
    const float* g1_w  = (const float*)d_in[10];
    const float* g1_b  = (const float*)d_in[11];
    const float* g2_w  = (const float*)d_in[12];
    const float* g2_b  = (const float*)d_in[13];
    const float* f1_w  = (const float*)d_in[14];
    const float* f1_b  = (const float*)d_in[15];
    const float* f2_w  = (const float*)d_in[16];
    const float* f2_b  = (const float*)d_in[17];
    float* out = (float*)d_out;

    float* ws    = (float*)d_ws;
    int*   slots = (int*)d_ws;                          // [0, 3200) ints
    int*   xgdone= (int*)d_ws + NBLK*SLOTP;             // [3200, 3456) ints
    int*   pcnt  = (int*)d_ws + NBLK*SLOTP + 8*SLOTP;   // [3456, 5504) ints
    _Float16* hF = (_Float16*)(ws + 16384);             // 2*4*16*512 f16 = 128 KB
    float* hqB  = ws + 16384 + 32768;                   // 64*512 f32
    float* xgT  = hqB + 64*512;                         // 2000*2048 f32
    float* part = xgT + (size_t)4*HIDD*MCOL;            // 256*100

    // 0. zero barrier slots + xg flags + pair counters (deterministic across replays)
    hipMemsetAsync(slots, 0, (NBLK + 8 + BATCH)*SLOTP*sizeof(int), stream);

    // 1. fused xg + LSTM: 356 blocks (100 lstm + 256 xg workers)
    k_mega<<<NBLK + NXG, 320, 0, stream>>>(sent, table, W_ih, b_ih, b_hh,
                                           hF, hqB, xgT, W_hh, h0, c0, lens,
                                           slots, xgdone);

    // 2. fused qp/ipjp + pair MFMA + final epilogue (256 blocks)
    k_pair5<<<BATCH*4, 256, 0, stream>>>(hqB, conv, g1_w, g1_b, g2_w, g2_b,
                                         f1_w, f1_b, f2_w, f2_b, part, pcnt, out);
}